// Round 5
// baseline (77.046 us; speedup 1.0000x reference)
//
#include <hip/hip_runtime.h>
#include <hip/hip_bf16.h>

// RZ gate dense matrix -> real-part float32, 4096x4096 (64 MiB), = cos(theta/2)*I.
// Verified passing in round 4 (absmax 0.0). This round: simplified per-row
// variant to confirm we are pinned at the write-BW roofline (the timed 75.6us
// is ~56us harness 0xAA poison fills + ~12-18us kernel; kernel floor is
// 64 MiB / 6.0 TB/s ~= 11us).
//
// One block per row: 256 threads x 4 float4 = 4096 floats = one row.
// Diagonal slot (float index == row) patched in-register; no divisions.

constexpr int N_QUBITS = 12;
constexpr int DIM      = 1 << N_QUBITS;   // 4096
constexpr int BLOCK    = 256;
constexpr int F4_PER_ROW = DIM / 4;       // 1024
constexpr int UNROLL   = F4_PER_ROW / BLOCK; // 4

__global__ __launch_bounds__(BLOCK)
void rz_real_row_kernel(const float* __restrict__ theta_p,
                        float*       __restrict__ out,
                        int          out_size)
{
    const float cv  = cosf(0.5f * theta_p[0]);
    const int   row = blockIdx.x;

    float4* rowp = (float4*)out + (size_t)row * F4_PER_ROW;
    const int diag_f4  = row >> 2;   // float4 index holding column `row`
    const int diag_lane = row & 3;   // component within that float4

#pragma unroll
    for (int i = 0; i < UNROLL; ++i) {
        const int f4 = threadIdx.x + i * BLOCK;          // coalesced
        float4 v = make_float4(0.f, 0.f, 0.f, 0.f);
        if (f4 == diag_f4) {
            if      (diag_lane == 0) v.x = cv;
            else if (diag_lane == 1) v.y = cv;
            else if (diag_lane == 2) v.z = cv;
            else                     v.w = cv;
        }
        rowp[f4] = v;
    }
}

// Safety fallback if out_size ever differs from DIM*DIM (not expected).
__global__ __launch_bounds__(BLOCK)
void rz_real_generic_kernel(const float* __restrict__ theta_p,
                            float*       __restrict__ out,
                            int          out_size)
{
    const float cv = cosf(0.5f * theta_p[0]);
    for (int idx = blockIdx.x * BLOCK + threadIdx.x; idx < out_size;
         idx += gridDim.x * BLOCK) {
        out[idx] = (idx % (DIM + 1) == 0 && (idx / (DIM + 1)) < DIM) ? cv : 0.f;
    }
}

extern "C" void kernel_launch(void* const* d_in, const int* in_sizes, int n_in,
                              void* d_out, int out_size, void* d_ws, size_t ws_size,
                              hipStream_t stream) {
    const float* theta = (const float*)d_in[0];
    float*       out   = (float*)d_out;

    if (out_size == DIM * DIM) {
        rz_real_row_kernel<<<DIM, BLOCK, 0, stream>>>(theta, out, out_size);
    } else {
        int grid = (out_size + BLOCK - 1) / BLOCK;
        if (grid > 65535) grid = 65535;
        if (grid < 1) grid = 1;
        rz_real_generic_kernel<<<grid, BLOCK, 0, stream>>>(theta, out, out_size);
    }
}